// Round 4
// baseline (80.957 us; speedup 1.0000x reference)
//
#include <hip/hip_runtime.h>

// Problem constants (match reference): B=8, D=H=W=128, C=2, fp32.
constexpr int Bc = 8, Dc = 128, Hc = 128, Wc = 128;

// 16B vector load at 8B-aligned addresses: CDNA global loads require only
// dword alignment, so global_load_dwordx4 at float2 granularity is fine.
typedef float float4v __attribute__((ext_vector_type(4)));
typedef float float2v __attribute__((ext_vector_type(2)));

__global__ __launch_bounds__(512) void affine_trilinear_kernel(
    const float* __restrict__ images,      // (B,D,H,W,C) fp32
    const float* __restrict__ mats,        // (B,3,4) fp32
    float* __restrict__ out)               // (B,D,H,W,C) fp32
{
    const int tid    = threadIdx.x;
    const int lane_w = tid & 63;           // 64 consecutive w per wave
    const int row    = tid >> 6;           // 8 rows per block, one per wave

    // XCD-chunked swizzle: HW round-robins blockIdx across the 8 XCDs, so
    // consecutive ORIGINAL indices (which share a d-slab / boundary rows)
    // would land on different per-XCD L2s. Remap so each XCD gets a
    // contiguous chunk of the original grid. nwg = 32768, 32768 % 8 == 0.
    const int bid  = blockIdx.x;
    const int orig = (bid & 7) * (32768 / 8) + (bid >> 3);

    const int wh = orig & 1;               // w half
    const int h8 = (orig >> 1) & 15;       // 8-row group
    const int d  = (orig >> 5) & (Dc - 1);
    const int b  = orig >> 12;             // uniform per block -> scalar

    const int w = wh * 64 + lane_w;
    const int h = h8 * 8 + row;

    const float* m = mats + b * 12;
    const float th00 = m[0] * 0.2f + 1.0f;
    const float th01 = m[1] * 0.2f;
    const float th02 = m[2] * 0.2f;
    const float th10 = m[4] * 0.2f;
    const float th11 = m[5] * 0.2f + 1.0f;
    const float th12 = m[6] * 0.2f;
    const float th20 = m[8] * 0.2f;
    const float th21 = m[9] * 0.2f;
    const float th22 = m[10] * 0.2f + 1.0f;
    const float t   = m[3] * 0.2f;                 // ref uses only m[0,3]
    const float off = 128.0f * (t + 0.5f) - 0.5f;  // dims are all 128

    // grid value: index - dim/2 - 0.5 = index - 64.5
    const float gx = (float)d - 64.5f;
    const float gy = (float)h - 64.5f;
    const float gz = (float)w - 64.5f;

    const float r0 = gx * th00 + gy * th01 + gz * th02 + off;
    const float r1 = gx * th10 + gy * th11 + gz * th12 + off;
    const float r2 = gx * th20 + gy * th21 + gz * th22 + off;

    const int i0 = (int)floorf(r0);
    const int i1 = (int)floorf(r1);
    const int i2 = (int)floorf(r2);

    // d,h axes: per-corner clamped loc + weight (vs CLAMPED loc, per ref).
    const int l0a = min(max(i0,     0), Dc - 1);
    const int l0b = min(max(i0 + 1, 0), Dc - 1);
    const int l1a = min(max(i1,     0), Hc - 1);
    const int l1b = min(max(i1 + 1, 0), Hc - 1);

    const float w0a = fmaxf(1.0f - fabsf(r0 - (float)l0a), 0.0f);
    const float w0b = fmaxf(1.0f - fabsf(r0 - (float)l0b), 0.0f);
    const float w1a = fmaxf(1.0f - fabsf(r1 - (float)l1a), 0.0f);
    const float w1b = fmaxf(1.0f - fabsf(r1 - (float)l1b), 0.0f);

    // w axis: both corners from ONE 16B pair load at bp (float2 elems
    // bp, bp+1). Remap corner weights onto (lo,hi) of the pair:
    //   interior       : wlo = w2a, whi = w2b
    //   i2 < 0  (clamp): both corners at elem 0   -> wlo = w2a+w2b, whi = 0
    //   i2 > 126(clamp): both corners at elem 127 -> wlo = 0, whi = w2a+w2b
    const int bp  = min(max(i2, 0), Wc - 2);
    const int l2a = min(max(i2,     0), Wc - 1);
    const int l2b = min(max(i2 + 1, 0), Wc - 1);
    const float w2a = fmaxf(1.0f - fabsf(r2 - (float)l2a), 0.0f);
    const float w2b = fmaxf(1.0f - fabsf(r2 - (float)l2b), 0.0f);
    const float wlo = (i2 > 126) ? 0.0f        : (w2a + ((i2 < 0) ? w2b : 0.0f));
    const float whi = (i2 > 126) ? (w2a + w2b) : ((i2 < 0) ? 0.0f : w2b);

    const float2* img = (const float2*)images + (size_t)b * (Dc * Hc * Wc);

    float acc0 = 0.0f, acc1 = 0.0f;
    #pragma unroll
    for (int s = 0; s < 4; ++s) {
        const int   l0  = (s & 2) ? l0b : l0a;
        const int   l1  = (s & 1) ? l1b : l1a;
        const float wdh = ((s & 2) ? w0b : w0a) * ((s & 1) ? w1b : w1a);
        const float4v v = *(const float4v*)(img + ((size_t)l0 * Hc + l1) * Wc + bp);
        acc0 = fmaf(v.x * wlo + v.z * whi, wdh, acc0);
        acc1 = fmaf(v.y * wlo + v.w * whi, wdh, acc1);
    }

    // Non-temporal store: keep the 134MB output stream from evicting image
    // lines out of L2 (proven FETCH reduction in R2).
    float2v o = {acc0, acc1};
    float2v* po = (float2v*)out + ((((size_t)b * Dc + d) * Hc + h) * Wc + w);
    __builtin_nontemporal_store(o, po);
}

extern "C" void kernel_launch(void* const* d_in, const int* in_sizes, int n_in,
                              void* d_out, int out_size, void* d_ws, size_t ws_size,
                              hipStream_t stream) {
    const float* images = (const float*)d_in[0];
    const float* mats   = (const float*)d_in[1];
    float* out          = (float*)d_out;

    const int threads = 512;               // 8 waves: 8 h-rows per block
    const int blocks  = Bc * Dc * 16 * 2;  // 32768: (b, d, h/8, w-half)
    affine_trilinear_kernel<<<blocks, threads, 0, stream>>>(images, mats, out);
}